// Round 1
// baseline (471.516 us; speedup 1.0000x reference)
//
#include <hip/hip_runtime.h>

#define NT    256
#define WPB   4           // waves per block, one row per wave
#define DIM   4096
#define EPL   64          // elements per lane (DIM / 64)
#define VPL   16          // float4 loads per lane
#define HBITS 11
#define HBINS 2048
#define HSTR  2072        // uint words per wave LDS region (16B-aligned, bank-staggered: 2072%32=24)

// wave-level cross-lane LDS handoff fence: drain DS + block compiler reordering
#define FENCE() asm volatile("s_waitcnt lgkmcnt(0)" ::: "memory")

// Order-preserving float->uint key: larger float <=> larger key.
__device__ __forceinline__ unsigned int f2key(float f) {
  unsigned int u = __float_as_uint(f);
  return u ^ (((unsigned int)((int)u >> 31)) | 0x80000000u);
}
__device__ __forceinline__ float key2f(unsigned int kk) {
  unsigned int m = ((unsigned int)((int)(~kk) >> 31)) | 0x80000000u;
  return __uint_as_float(kk ^ m);
}

__global__ __launch_bounds__(NT, 4) void topk_mask_kernel(
    const float* __restrict__ x, float* __restrict__ out,
    int k, int rows) {
  __shared__ unsigned int lds[WPB * HSTR];
  const int tid  = threadIdx.x;
  const int lane = tid & 63;
  const int wv   = tid >> 6;
  const int row  = blockIdx.x * WPB + wv;
  if (row >= rows) return;

  unsigned int* H  = lds + wv * HSTR;   // wave-private region
  uint4*        H4 = (uint4*)H;

  // ---- clear 2048-bin histogram (uint4 stores, conflict-free) ----
  uint4 z; z.x = z.y = z.z = z.w = 0u;
#pragma unroll
  for (int i = 0; i < 8; ++i) H4[i * 64 + lane] = z;

  // ---- load full row: 16 dense-coalesced float4/lane; keys in registers ----
  const long base = (long)row * DIM;
  const float4* xv = (const float4*)(x + base);
  unsigned int key[EPL];
#pragma unroll
  for (int j = 0; j < VPL; ++j) {
    float4 v = xv[j * 64 + lane];
    key[4*j+0] = f2key(v.x);
    key[4*j+1] = f2key(v.y);
    key[4*j+2] = f2key(v.z);
    key[4*j+3] = f2key(v.w);
  }

  FENCE();   // clears visible before cross-lane atomics

  // ---- pass 1: histogram of top-11 bits (sign+exp+2 mantissa: hot bin ~5%) ----
#pragma unroll
  for (int e = 0; e < EPL; ++e)
    atomicAdd(&H[key[e] >> (32 - HBITS)], 1u);

  FENCE();   // counts visible before scan reads

  // ---- wave suffix-scan over 2048 bins; lane owns bins [32*lane, 32*lane+32) ----
  unsigned int S = 0;
#pragma unroll
  for (int s8 = 0; s8 < 8; ++s8) {
    int i = (s8 + lane) & 7;            // rotate reads to spread banks
    uint4 h = H4[(lane << 3) + i];
    S += h.x + h.y + h.z + h.w;
  }
  unsigned int T = S;                   // suffix-inclusive sum over lanes >= lane
#pragma unroll
  for (int off = 1; off < 64; off <<= 1) {
    unsigned int v = __shfl_down(T, off);
    if (lane + off < 64) T += v;
  }
  unsigned int krem = (unsigned int)k;
  bool crossL = (T - S < krem) && (krem <= T);       // exactly one lane
  unsigned long long balL = __ballot(crossL);
  int L = __ffsll(balL) - 1;
  unsigned int TL1 = __shfl(T - S, L);               // count in bins >= 32*(L+1)

  // refine within lane L's 32 bins cooperatively (lanes 0..31)
  unsigned int h1 = H[(L << 5) + (lane & 31)];
  unsigned int s32 = h1;
#pragma unroll
  for (int off = 1; off < 32; off <<= 1) {
    unsigned int v = __shfl_down(s32, off);
    if ((lane & 31) + off < 32) s32 += v;
  }
  unsigned int exclb = TL1 + s32 - h1;               // # elems in bins > this bin
  bool crossB = (lane < 32) && (exclb < krem) && (krem <= TL1 + s32);
  unsigned long long balB = __ballot(crossB);
  int ib = __ffsll(balB) - 1;
  unsigned int b0     = ((unsigned int)L << 5) + (unsigned int)ib;
  unsigned int excls  = __shfl(exclb, ib);
  unsigned int ccount = __shfl(h1, ib);              // elems sharing the 11-bit prefix
  krem -= excls;                                     // rank within bin b0 (1-based)

  // ---- per-lane match masks: key's top 11 bits == b0 ----
  unsigned int mlo = 0, mhi = 0;
#pragma unroll
  for (int e = 0; e < 32; ++e)
    mlo |= ((key[e] >> (32 - HBITS)) == b0 ? 1u : 0u) << e;
#pragma unroll
  for (int e = 0; e < 32; ++e)
    mhi |= ((key[e + 32] >> (32 - HBITS)) == b0 ? 1u : 0u) << e;

  unsigned int t, r, ce;

  if (ccount <= 64u) {
    // ---- fast path (data-typical): compact candidates to LDS, rank in-wave ----
    unsigned int mc = (unsigned int)(__popc(mlo) + __popc(mhi));
    unsigned int p = mc;
#pragma unroll
    for (int off = 1; off < 64; off <<= 1) {
      unsigned int v = __shfl_up(p, off);
      if (lane >= off) p += v;
    }
    unsigned int slot = p - mc;                      // exclusive wave prefix
#pragma unroll
    for (int e = 0; e < 32; ++e)
      if ((mlo >> e) & 1u) H[slot++] = key[e];
#pragma unroll
    for (int e = 0; e < 32; ++e)
      if ((mhi >> e) & 1u) H[slot++] = key[e + 32];
    FENCE();
    unsigned int cv = 0;
    if (lane < (int)ccount) cv = H[lane];
    unsigned int g = 0, eqc = 0;
    for (unsigned int l = 0; l < ccount; ++l) {      // ~7 iters typical
      unsigned int bc = __shfl(cv, (int)l);
      g   += (bc > cv)  ? 1u : 0u;
      eqc += (bc == cv) ? 1u : 0u;
    }
    bool ok = ((unsigned int)lane < ccount) && (g < krem) && (krem <= g + eqc);
    unsigned long long balS = __ballot(ok);
    int sl = __ffsll(balS) - 1;
    t  = __shfl(cv, sl);                             // the k-th largest key
    r  = krem - __shfl(g, sl);                       // # equals to keep
    ce = __shfl(eqc, sl);                            // total equals
  } else {
    // ---- robust fallback: 3 more radix passes of 7 bits (128 bins) ----
    t = b0 << (32 - HBITS);
#pragma unroll
    for (int pass = 0; pass < 3; ++pass) {
      const int shift = 14 - 7 * pass;
      H[lane] = 0; H[lane + 64] = 0;
      FENCE();
#pragma unroll
      for (int e = 0; e < 32; ++e)
        if ((mlo >> e) & 1u) atomicAdd(&H[(key[e] >> shift) & 127u], 1u);
#pragma unroll
      for (int e = 0; e < 32; ++e)
        if ((mhi >> e) & 1u) atomicAdd(&H[(key[e + 32] >> shift) & 127u], 1u);
      FENCE();
      unsigned int hh0 = H[2 * lane], hh1 = H[2 * lane + 1];
      unsigned int Sp = hh0 + hh1;
      unsigned int Tp = Sp;
#pragma unroll
      for (int off = 1; off < 64; off <<= 1) {
        unsigned int v = __shfl_down(Tp, off);
        if (lane + off < 64) Tp += v;
      }
      unsigned int Tn = Tp - Sp;                     // suffix excl this lane's 2 bins
      bool c1 = (Tn < krem) && (krem <= Tn + hh1);   // upper bin crosses
      bool c0 = (Tn + hh1 < krem) && (krem <= Tp);   // lower bin crosses
      unsigned long long bb1 = __ballot(c1);
      unsigned long long bb0 = __ballot(c0);
      unsigned int selbin, excl2;
      if (bb1) {
        int s2 = __ffsll(bb1) - 1;
        selbin = 2u * (unsigned int)s2 + 1u;
        excl2  = __shfl(Tn, s2);
      } else {
        int s2 = __ffsll(bb0) - 1;
        selbin = 2u * (unsigned int)s2;
        excl2  = __shfl(Tn + hh1, s2);
      }
      krem -= excl2;
      t |= selbin << shift;
#pragma unroll
      for (int e = 0; e < 32; ++e)
        if (((key[e] >> shift) & 127u) != selbin) mlo &= ~(1u << e);
#pragma unroll
      for (int e = 0; e < 32; ++e)
        if (((key[e + 32] >> shift) & 127u) != selbin) mhi &= ~(1u << e);
    }
    unsigned int ec = (unsigned int)(__popc(mlo) + __popc(mhi));
    unsigned int tot = ec;
#pragma unroll
    for (int off = 1; off < 64; off <<= 1) tot += __shfl_xor(tot, off);
    ce = tot;
    r  = krem;
  }

  // ---- write output (coalesced float4) ----
  float4* ov = (float4*)(out + base);
  if (r == ce) {
    // common case: keep every element >= t
#pragma unroll
    for (int j = 0; j < VPL; ++j) {
      float4 o; float* op = (float*)&o;
#pragma unroll
      for (int c = 0; c < 4; ++c) {
        unsigned int kk = key[4*j + c];
        op[c] = (kk >= t) ? key2f(kk) : 0.0f;
      }
      ov[j * 64 + lane] = o;
    }
  } else {
    // rare ties at boundary: keep first r equals in ascending linear index
    // linear idx = 256*j + 4*lane + c  ->  order: j major, lane, then c
    unsigned int elo = 0, ehi = 0;
#pragma unroll
    for (int e = 0; e < 32; ++e) elo |= (key[e] == t ? 1u : 0u) << e;
#pragma unroll
    for (int e = 0; e < 32; ++e) ehi |= (key[e + 32] == t ? 1u : 0u) << e;
    unsigned int run = 0;
#pragma unroll
    for (int j = 0; j < VPL; ++j) {
      unsigned int nib = ((j < 8) ? (elo >> (4*j)) : (ehi >> (4*j - 32))) & 0xFu;
      unsigned int cnt = (unsigned int)__popc(nib);
      unsigned int pp = cnt;
#pragma unroll
      for (int off = 1; off < 64; off <<= 1) {
        unsigned int v = __shfl_up(pp, off);
        if (lane >= off) pp += v;
      }
      unsigned int totj = __shfl(pp, 63);
      H[j * 64 + lane] = run + pp - cnt;   // per-(lane,j) eq-rank base (stash in LDS)
      run += totj;
    }
#pragma unroll
    for (int j = 0; j < VPL; ++j) {
      unsigned int bj  = H[j * 64 + lane];  // same-lane same-address: no fence needed
      unsigned int nib = ((j < 8) ? (elo >> (4*j)) : (ehi >> (4*j - 32))) & 0xFu;
      float4 o; float* op = (float*)&o;
#pragma unroll
      for (int c = 0; c < 4; ++c) {
        unsigned int kk = key[4*j + c];
        bool eq = (nib >> c) & 1u;
        unsigned int rk = bj + (unsigned int)__popc(nib & ((1u << c) - 1u));
        bool keep = (kk > t) || (eq && rk < r);
        op[c] = keep ? key2f(kk) : 0.0f;
      }
      ov[j * 64 + lane] = o;
    }
  }
}

extern "C" void kernel_launch(void* const* d_in, const int* in_sizes, int n_in,
                              void* d_out, int out_size, void* d_ws, size_t ws_size,
                              hipStream_t stream) {
  const float* x = (const float*)d_in[0];
  float* out = (float*)d_out;
  const int rows = in_sizes[0] / DIM;     // 4*4096 = 16384
  const int k = DIM / 2;                  // TOPK==0 -> k = D/2
  const int blocks = (rows + WPB - 1) / WPB;
  topk_mask_kernel<<<blocks, NT, 0, stream>>>(x, out, k, rows);
}

// Round 3
// 432.518 us; speedup vs baseline: 1.0902x; 1.0902x over previous
//
#include <hip/hip_runtime.h>

#define NT    256        // one block = one row, 4 waves
#define DIM   4096
#define VPT   4          // float4 loads per thread
#define EPT   16         // elements per thread
#define HBITS 11
#define HBINS 2048       // u32 bins, 8 KB

// Order-preserving float->uint key: larger float <=> larger key.
__device__ __forceinline__ unsigned int f2key(float f) {
  unsigned int u = __float_as_uint(f);
  return (u & 0x80000000u) ? ~u : (u | 0x80000000u);
}
__device__ __forceinline__ float key2f(unsigned int kk) {
  unsigned int u = (kk & 0x80000000u) ? (kk & 0x7FFFFFFFu) : ~kk;
  return __uint_as_float(u);
}

__global__ __launch_bounds__(NT) void topk_mask_kernel(
    const float* __restrict__ x, float* __restrict__ out, int k) {
  __shared__ unsigned int H[HBINS];          // histogram / scratch bins
  __shared__ unsigned int CK[64];            // candidate keys
  __shared__ unsigned int CP[64];            // candidate positions
  __shared__ unsigned int wtot[4];
  __shared__ unsigned int sh_ctr, sh_selb, sh_sexcl, sh_scnt,
                          sh_keep0, sh_keep1, sh_run;

  const int tid  = threadIdx.x;
  const int lane = tid & 63;
  const int wv   = tid >> 6;
  const long base = (long)blockIdx.x * DIM;

  // ---- clear histogram (2 uint4 stores/thread) ----
  uint4 z; z.x = z.y = z.z = z.w = 0u;
  ((uint4*)H)[tid]      = z;
  ((uint4*)H)[NT + tid] = z;
  if (tid == 0) sh_ctr = 0;
  __syncthreads();

  // ---- fused load + key conversion + 11-bit histogram ----
  const float4* xv = (const float4*)(x + base);
  unsigned int key[EPT];
#pragma unroll
  for (int j = 0; j < VPT; ++j) {
    float4 v = xv[j * NT + tid];
    unsigned int a = f2key(v.x), b = f2key(v.y),
                 c = f2key(v.z), d = f2key(v.w);
    key[4*j+0] = a; key[4*j+1] = b; key[4*j+2] = c; key[4*j+3] = d;
    atomicAdd(&H[a >> (32 - HBITS)], 1u);
    atomicAdd(&H[b >> (32 - HBITS)], 1u);
    atomicAdd(&H[c >> (32 - HBITS)], 1u);
    atomicAdd(&H[d >> (32 - HBITS)], 1u);
  }
  __syncthreads();

  // ---- block suffix-scan: thread owns 8 consecutive bins ----
  uint4 ha = ((uint4*)H)[2 * tid];
  uint4 hb = ((uint4*)H)[2 * tid + 1];
  unsigned int h[8] = {ha.x, ha.y, ha.z, ha.w, hb.x, hb.y, hb.z, hb.w};
  unsigned int S = h[0]+h[1]+h[2]+h[3]+h[4]+h[5]+h[6]+h[7];
  unsigned int T = S;                         // suffix-inclusive over threads >= tid
#pragma unroll
  for (int off = 1; off < 64; off <<= 1) {
    unsigned int v = __shfl_down(T, off);
    if (lane + off < 64) T += v;
  }
  if (lane == 0) wtot[wv] = T;
  __syncthreads();
#pragma unroll
  for (int w = 0; w < 4; ++w)
    if (w > wv) T += wtot[w];

  unsigned int krem = (unsigned int)k;
  unsigned int A = T - S;                     // count in bins above this thread's
  if (A < krem && krem <= T) {                // crossing thread (unique)
    unsigned int acc = A;
#pragma unroll
    for (int i = 7; i >= 0; --i) {            // walk own bins high->low
      if (acc < krem && krem <= acc + h[i]) { // crossing bin (unique)
        sh_selb  = (unsigned int)(tid * 8 + i);
        sh_sexcl = acc;
        sh_scnt  = h[i];
      }
      acc += h[i];
    }
  }
  __syncthreads();

  unsigned int cc = sh_scnt;                  // elems sharing the 11-bit prefix
  krem -= sh_sexcl;                           // rank within selected bin (1-based)
  unsigned int pref = sh_selb << (32 - HBITS);
  unsigned int plen = HBITS;
  unsigned int s    = 32 - HBITS;

  // ---- rare: refine prefix 7 bits at a time until candidates fit one wave ----
  while (cc > 64u && plen < 32u) {
    const unsigned int nb  = (32u - plen < 7u) ? (32u - plen) : 7u;
    const unsigned int s2  = 32u - plen - nb;
    const unsigned int msk = (1u << nb) - 1u;
    if (tid < 128) H[tid] = 0;
    __syncthreads();
    const unsigned int psl = pref >> s;
#pragma unroll
    for (int e = 0; e < EPT; ++e)
      if ((key[e] >> s) == psl)
        atomicAdd(&H[(key[e] >> s2) & msk], 1u);
    __syncthreads();
    if (wv == 0) {                            // wave 0 scans <=128 bins, 2/lane
      unsigned int h0 = H[2 * lane], h1 = H[2 * lane + 1];
      unsigned int Tp = h0 + h1;
      const unsigned int Sp = Tp;
#pragma unroll
      for (int off = 1; off < 64; off <<= 1) {
        unsigned int v = __shfl_down(Tp, off);
        if (lane + off < 64) Tp += v;
      }
      unsigned int Tn = Tp - Sp;              // count above both my bins
      if (Tn < krem && krem <= Tn + h1) {
        sh_selb = 2u*(unsigned int)lane + 1u; sh_sexcl = Tn;      sh_scnt = h1;
      } else if (Tn + h1 < krem && krem <= Tn + h1 + h0) {
        sh_selb = 2u*(unsigned int)lane;      sh_sexcl = Tn + h1; sh_scnt = h0;
      }
    }
    __syncthreads();
    cc    = sh_scnt;
    krem -= sh_sexcl;
    pref |= sh_selb << s2;
    plen += nb;
    s     = s2;
  }

  float4* ov = (float4*)(out + base);
  const unsigned int ps = pref >> s;

  if (cc <= 64u) {
    // ---- fast path: compact candidates to LDS, rank in wave 0 ----
    unsigned int cmask = 0;
#pragma unroll
    for (int e = 0; e < EPT; ++e)
      cmask |= ((key[e] >> s) == ps ? 1u : 0u) << e;
    const unsigned int nc = (unsigned int)__popc(cmask);
    unsigned int mybase = 0;
    if (nc) {
      mybase = atomicAdd(&sh_ctr, nc);
      unsigned int i = mybase;
#pragma unroll
      for (int e = 0; e < EPT; ++e)
        if ((cmask >> e) & 1u) {
          CK[i] = key[e];
          CP[i] = (unsigned int)(((e >> 2) * NT + tid) * 4 + (e & 3));
          ++i;
        }
    }
    __syncthreads();
    if (wv == 0) {
      unsigned int cv = (lane < (int)cc) ? CK[lane] : 0u;
      unsigned int pv = (lane < (int)cc) ? CP[lane] : 0xFFFFFFFFu;
      unsigned int rank = 0;                  // (value desc, index asc) rank
      for (unsigned int l = 0; l < cc; ++l) {
        unsigned int bc = __shfl(cv, (int)l);
        unsigned int bp = __shfl(pv, (int)l);
        rank += (bc > cv || (bc == cv && bp < pv)) ? 1u : 0u;
      }
      bool keep = ((unsigned int)lane < cc) && (rank < krem);
      unsigned long long bal = __ballot(keep);
      if (lane == 0) {
        sh_keep0 = (unsigned int)bal;
        sh_keep1 = (unsigned int)(bal >> 32);
      }
    }
    __syncthreads();
    const unsigned int k0 = sh_keep0, k1 = sh_keep1;
    unsigned int slot = mybase;               // slots assigned in e-order
#pragma unroll
    for (int j = 0; j < VPT; ++j) {
      float4 o; float* op = (float*)&o;
#pragma unroll
      for (int c = 0; c < 4; ++c) {
        const int e = 4*j + c;
        const unsigned int kk = key[e];
        bool kp = (kk >> s) > ps;             // strictly higher bin: keep
        if ((cmask >> e) & 1u) {
          kp = (((slot < 32u) ? k0 : k1) >> (slot & 31u)) & 1u;
          ++slot;
        }
        op[c] = kp ? key2f(kk) : 0.0f;
      }
      ov[j * NT + tid] = o;
    }
  } else {
    // ---- degenerate: >64 exact duplicates of t; keep first r by index ----
    const unsigned int t = pref;
    const unsigned int r = krem;
    unsigned int em = 0;
#pragma unroll
    for (int e = 0; e < EPT; ++e) em |= (key[e] == t ? 1u : 0u) << e;
    if (tid == 0) sh_run = 0;
    __syncthreads();
    unsigned int keepm = 0;
    for (int j = 0; j < VPT; ++j) {
      unsigned int nib = (em >> (4*j)) & 0xFu;
      unsigned int cnt = (unsigned int)__popc(nib);
      unsigned int p = cnt;                   // inclusive prefix over threads
#pragma unroll
      for (int off = 1; off < 64; off <<= 1) {
        unsigned int v = __shfl_up(p, off);
        if (lane >= off) p += v;
      }
      if (lane == 63) wtot[wv] = p;
      __syncthreads();
      unsigned int woff = 0;
#pragma unroll
      for (int w = 0; w < 4; ++w)
        if (w < wv) woff += wtot[w];
      unsigned int mb = sh_run + woff + (p - cnt);
#pragma unroll
      for (int c = 0; c < 4; ++c) {
        const int e = 4*j + c;
        if ((nib >> c) & 1u) { if (mb < r) keepm |= 1u << e; ++mb; }
      }
      __syncthreads();
      if (tid == 0) sh_run += wtot[0] + wtot[1] + wtot[2] + wtot[3];
      __syncthreads();
    }
#pragma unroll
    for (int j = 0; j < VPT; ++j) {
      float4 o; float* op = (float*)&o;
#pragma unroll
      for (int c = 0; c < 4; ++c) {
        const int e = 4*j + c;
        const unsigned int kk = key[e];
        op[c] = ((kk > t) || ((keepm >> e) & 1u)) ? key2f(kk) : 0.0f;
      }
      ov[j * NT + tid] = o;
    }
  }
}

extern "C" void kernel_launch(void* const* d_in, const int* in_sizes, int n_in,
                              void* d_out, int out_size, void* d_ws, size_t ws_size,
                              hipStream_t stream) {
  const float* x = (const float*)d_in[0];
  float* out = (float*)d_out;
  const int rows = in_sizes[0] / DIM;   // 4*4096 = 16384
  const int k = DIM / 2;                // TOPK==0 -> k = D/2
  topk_mask_kernel<<<rows, NT, 0, stream>>>(x, out, k);
}